// Round 7
// baseline (258.245 us; speedup 1.0000x reference)
//
#include <hip/hip_runtime.h>
#include <hip/hip_bf16.h>

typedef __attribute__((ext_vector_type(8))) __bf16 bf16x8;
typedef __attribute__((ext_vector_type(4))) __bf16 bf16x4;
typedef __attribute__((ext_vector_type(4))) float f32x4;

constexpr int B = 4, S = 2048, D = 1024, H = 16, DK = 64;

#define GLOAD16(gp, lp)                                                              \
  __builtin_amdgcn_global_load_lds((const __attribute__((address_space(1))) void*)(gp), \
                                   (__attribute__((address_space(3))) void*)(lp), 16, 0, 0)

// ---------------------------------------------------------------------------
// Kernel 0: one-shot f32 -> bf16 conversion of X, w_qkv, w_o into workspace.
// ---------------------------------------------------------------------------
__global__ __launch_bounds__(256) void convert_bf16(const float* __restrict__ X,
                                                    const float* __restrict__ Wqkv,
                                                    const float* __restrict__ Wo,
                                                    __bf16* __restrict__ Xb,
                                                    __bf16* __restrict__ Wqkvb,
                                                    __bf16* __restrict__ Wob) {
  const int NX = B * S * D;
  const int NW = 3 * D * D;
  const int NO = D * D;
  const int total8 = (NX + NW + NO) / 8;
  for (int i = blockIdx.x * blockDim.x + threadIdx.x; i < total8;
       i += gridDim.x * blockDim.x) {
    const int e = i * 8;
    const float* src;
    __bf16* dst;
    int off;
    if (e < NX) {
      src = X; dst = Xb; off = e;
    } else if (e < NX + NW) {
      src = Wqkv; dst = Wqkvb; off = e - NX;
    } else {
      src = Wo; dst = Wob; off = e - NX - NW;
    }
    float4 a = *reinterpret_cast<const float4*>(src + off);
    float4 b = *reinterpret_cast<const float4*>(src + off + 4);
    bf16x8 v = {(__bf16)a.x, (__bf16)a.y, (__bf16)a.z, (__bf16)a.w,
                (__bf16)b.x, (__bf16)b.y, (__bf16)b.z, (__bf16)b.w};
    *reinterpret_cast<bf16x8*>(dst + off) = v;
  }
}

// ---------------------------------------------------------------------------
// Kernel 1 (m97 structure): qkv = Xb @ Wqkvb^T + b ; scatter to Q (scaled by
// 0.125*log2(e)), K, V^T, all bf16. 128x128 tile, BK=64, gload_lds staging.
// ---------------------------------------------------------------------------
__global__ __launch_bounds__(256) void qkv_gemm(const __bf16* __restrict__ Xb,
                                                const __bf16* __restrict__ Wb,
                                                const float* __restrict__ bias,
                                                __bf16* __restrict__ Qb,
                                                __bf16* __restrict__ Kb,
                                                __bf16* __restrict__ VTb) {
  __shared__ __bf16 As[128 * 64];
  __shared__ __bf16 Bs[128 * 64];
  const int tid = threadIdx.x;
  const int lane = tid & 63;
  const int w = tid >> 6;
  const int wr = w >> 1, wc = w & 1;
  const int lr = lane & 15, lb = lane >> 4;
  const int m0 = blockIdx.x * 128, n0 = blockIdx.y * 128;

  int srow[4], sgcol[4];
#pragma unroll
  for (int rnd = 0; rnd < 4; ++rnd) {
    const int i = rnd * 256 + tid;
    srow[rnd] = i >> 3;
    sgcol[rnd] = ((i & 7) ^ (srow[rnd] & 7)) << 3;
  }

  f32x4 acc[4][4];
#pragma unroll
  for (int i = 0; i < 4; ++i)
#pragma unroll
    for (int j = 0; j < 4; ++j) acc[i][j] = f32x4{0.f, 0.f, 0.f, 0.f};

  for (int k0 = 0; k0 < D; k0 += 64) {
#pragma unroll
    for (int rnd = 0; rnd < 4; ++rnd) {
      GLOAD16(&Xb[(size_t)(m0 + srow[rnd]) * D + k0 + sgcol[rnd]],
              (char*)As + rnd * 4096 + w * 1024);
      GLOAD16(&Wb[(size_t)(n0 + srow[rnd]) * D + k0 + sgcol[rnd]],
              (char*)Bs + rnd * 4096 + w * 1024);
    }
    __syncthreads();

    bf16x8 af[4][2], bfr[4][2];
#pragma unroll
    for (int m = 0; m < 4; ++m) {
      const int row = wr * 64 + m * 16 + lr;
#pragma unroll
      for (int ks = 0; ks < 2; ++ks)
        af[m][ks] = *reinterpret_cast<const bf16x8*>(
            (const char*)As + row * 128 + (((ks * 32 + lb * 8) << 1) ^ ((row & 7) << 4)));
    }
#pragma unroll
    for (int n = 0; n < 4; ++n) {
      const int row = wc * 64 + n * 16 + lr;
#pragma unroll
      for (int ks = 0; ks < 2; ++ks)
        bfr[n][ks] = *reinterpret_cast<const bf16x8*>(
            (const char*)Bs + row * 128 + (((ks * 32 + lb * 8) << 1) ^ ((row & 7) << 4)));
    }
#pragma unroll
    for (int m = 0; m < 4; ++m)
#pragma unroll
      for (int n = 0; n < 4; ++n) {
        acc[m][n] = __builtin_amdgcn_mfma_f32_16x16x32_bf16(af[m][0], bfr[n][0], acc[m][n], 0, 0, 0);
        acc[m][n] = __builtin_amdgcn_mfma_f32_16x16x32_bf16(af[m][1], bfr[n][1], acc[m][n], 0, 0, 0);
      }
    __syncthreads();
  }

  const int seg = n0 >> 10;
#pragma unroll
  for (int m = 0; m < 4; ++m)
#pragma unroll
    for (int n = 0; n < 4; ++n) {
      const int c = n0 + wc * 64 + n * 16 + lr;
      const int cc = c & 1023;
      const int h = cc >> 6, dk = cc & 63;
      const float bv = bias[c];
#pragma unroll
      for (int r = 0; r < 4; ++r) {
        const int t = m0 + wr * 64 + m * 16 + lb * 4 + r;
        const int bb = t >> 11;
        const int s = t & 2047;
        const float v = acc[m][n][r] + bv;
        const size_t bh = (size_t)bb * H + h;
        if (seg == 0)
          Qb[(bh * S + s) * DK + dk] = (__bf16)(v * 0.180336893f);  // 0.125*log2(e)
        else if (seg == 1)
          Kb[(bh * S + s) * DK + dk] = (__bf16)v;
        else
          VTb[(bh * DK + dk) * S + s] = (__bf16)v;
      }
    }
}

// ---------------------------------------------------------------------------
// Kernel 2 (round 6 rewrite): block-cooperative causal flash attention.
// 8 waves/block (512 thr); wave w owns q-rows [qt*256+w*32, +32). Grid 512 =
// 8 qt-tiles x 64 bh -> exactly 2 blocks/CU resident (69.6KB LDS), 16
// waves/CU. Decode: xcd=flat&7, hg=flat>>6, s=(flat>>3)&7;
// bh=hg*8+xcd (head->XCD L2 locality); qt = (hg>=4) ? s : 7-s, so blocks
// flat and flat+256 (same CU under round-robin) have complementary depths
// (36 tile-units per CU). KVBLK=64, K/V staged once per block via
// global_load_lds w16 (linear dest + pre-swizzled source col, swizzled
// ds_read). ONE barrier per tile: the pre-staging barrier is redundant --
// staging writes buf[(t+1)&1], whose last readers finished before the
// previous iteration's end-barrier.
// Swapped QK^T; softmax in exp2 domain; defer-max THR=11.
// ---------------------------------------------------------------------------
__global__ __launch_bounds__(512) void attn_fwd(const __bf16* __restrict__ Qb,
                                                const __bf16* __restrict__ Kb,
                                                const __bf16* __restrict__ VTb,
                                                __bf16* __restrict__ AO) {
  __shared__ __bf16 Kl[2][64 * 64];
  __shared__ __bf16 Vl[2][64 * 64];
  __shared__ __bf16 Ps[8][32][72];
  const int tid = threadIdx.x;
  const int lane = tid & 63;
  const int w = tid >> 6;
  const int lr = lane & 15, lb = lane >> 4;

  const int flat = blockIdx.x;
  const int xcd = flat & 7;
  const int hg = flat >> 6;
  const int s_slot = (flat >> 3) & 7;
  const int bh = hg * 8 + xcd;
  const int qt = (hg >= 4) ? s_slot : 7 - s_slot;
  const int q0 = qt * 256 + w * 32;
  const int bb = bh >> 4, h = bh & 15;

  const __bf16* Q = Qb + (size_t)bh * S * DK;
  const __bf16* K = Kb + (size_t)bh * S * DK;
  const __bf16* VT = VTb + (size_t)bh * DK * S;

  const int nt = qt * 4 + 4;              // block trip count
  const int ntw = qt * 4 + (w >> 1) + 1;  // this wave's compute trips

  // staging: 512 threads cover one 64x64 bf16 tile (8KB) per instruction
  const int srow = tid >> 3;                       // 0..63
  const int sgcol = ((tid & 7) ^ (srow & 7)) << 3; // pre-swizzled source col
  const int ldst = w * 1024 + lane * 16;           // linear LDS byte offset

  bf16x8 qf[2][2];
#pragma unroll
  for (int m = 0; m < 2; ++m)
#pragma unroll
    for (int d = 0; d < 2; ++d)
      qf[m][d] = *reinterpret_cast<const bf16x8*>(
          &Q[(size_t)(q0 + m * 16 + lr) * DK + d * 32 + lb * 8]);

  // prologue: stage tile 0 into buffer 0
  GLOAD16(K + (size_t)srow * DK + sgcol, (char*)&Kl[0][0] + ldst);
  GLOAD16(VT + (size_t)srow * S + sgcol, (char*)&Vl[0][0] + ldst);
  __syncthreads();  // compiler drains vmcnt before s_barrier

  f32x4 o[2][4];
#pragma unroll
  for (int m = 0; m < 2; ++m)
#pragma unroll
    for (int n = 0; n < 4; ++n) o[m][n] = f32x4{0.f, 0.f, 0.f, 0.f};
  float mrun[2], lrun[2];  // per q = lr, exp2 domain
#pragma unroll
  for (int m = 0; m < 2; ++m) {
    mrun[m] = -1e30f;
    lrun[m] = 0.f;
  }

  for (int t = 0; t < nt; ++t) {
    const int cur = t & 1;
    const int kv0 = t * 64;
    if (t + 1 < nt) {  // issue next-tile staging early; latency hides under compute
      GLOAD16(K + ((size_t)(kv0 + 64) + srow) * DK + sgcol, (char*)&Kl[cur ^ 1][0] + ldst);
      GLOAD16(VT + (size_t)srow * S + (kv0 + 64) + sgcol, (char*)&Vl[cur ^ 1][0] + ldst);
    }

    if (t < ntw) {
      const char* kbase = (const char*)&Kl[cur][0];
      const char* vbase = (const char*)&Vl[cur][0];
      bf16x8 kf[4][2];
#pragma unroll
      for (int kc = 0; kc < 4; ++kc) {
        const int row = kc * 16 + lr;
#pragma unroll
        for (int d = 0; d < 2; ++d)
          kf[kc][d] = *reinterpret_cast<const bf16x8*>(
              kbase + row * 128 + ((d * 64 + lb * 16) ^ ((row & 7) << 4)));
      }

      // swapped QK^T: st[m][kc][r] = S^T[k=kv0+kc*16+4lb+r][q=q0+m*16+lr]
      f32x4 st[2][4];
      __builtin_amdgcn_s_setprio(1);
#pragma unroll
      for (int m = 0; m < 2; ++m)
#pragma unroll
        for (int kc = 0; kc < 4; ++kc) {
          f32x4 z = f32x4{0.f, 0.f, 0.f, 0.f};
          z = __builtin_amdgcn_mfma_f32_16x16x32_bf16(kf[kc][0], qf[m][0], z, 0, 0, 0);
          z = __builtin_amdgcn_mfma_f32_16x16x32_bf16(kf[kc][1], qf[m][1], z, 0, 0, 0);
          st[m][kc] = z;
        }
      __builtin_amdgcn_s_setprio(0);

      if (t == ntw - 1) {  // diagonal tile: mask k > q
#pragma unroll
        for (int m = 0; m < 2; ++m) {
          const int qg = q0 + m * 16 + lr;
#pragma unroll
          for (int kc = 0; kc < 4; ++kc)
#pragma unroll
            for (int r = 0; r < 4; ++r) {
              const int kg = kv0 + kc * 16 + 4 * lb + r;
              if (kg > qg) st[m][kc][r] = -1e30f;
            }
        }
      }

#pragma unroll
      for (int m = 0; m < 2; ++m) {
        float mx = st[m][0][0];
#pragma unroll
        for (int kc = 0; kc < 4; ++kc)
#pragma unroll
          for (int r = 0; r < 4; ++r) mx = fmaxf(mx, st[m][kc][r]);
        mx = fmaxf(mx, __shfl_xor(mx, 16, 64));
        mx = fmaxf(mx, __shfl_xor(mx, 32, 64));

        if (__any(mx > mrun[m] + 11.f)) {  // defer-max (exp2 domain)
          const float nm = fmaxf(mrun[m], mx);
          const float alpha = exp2f(mrun[m] - nm);
          mrun[m] = nm;
          lrun[m] *= alpha;
#pragma unroll
          for (int r = 0; r < 4; ++r) {
            const float ao = __shfl(alpha, 4 * lb + r, 64);
#pragma unroll
            for (int n = 0; n < 4; ++n) o[m][n][r] *= ao;
          }
        }

        float rs = 0.f;
#pragma unroll
        for (int kc = 0; kc < 4; ++kc) {
          bf16x4 pk;
#pragma unroll
          for (int r = 0; r < 4; ++r) {
            const float p = exp2f(st[m][kc][r] - mrun[m]);
            rs += p;
            pk[r] = (__bf16)p;
          }
          *reinterpret_cast<bf16x4*>(&Ps[w][m * 16 + lr][kc * 16 + 4 * lb]) = pk;
        }
        rs += __shfl_xor(rs, 16, 64);
        rs += __shfl_xor(rs, 32, 64);
        lrun[m] += rs;
      }

      asm volatile("s_waitcnt lgkmcnt(0)" ::: "memory");
      __builtin_amdgcn_sched_barrier(0);

      bf16x8 pa[2][2];
#pragma unroll
      for (int m = 0; m < 2; ++m)
#pragma unroll
        for (int ks = 0; ks < 2; ++ks)
          pa[m][ks] = *reinterpret_cast<const bf16x8*>(&Ps[w][m * 16 + lr][ks * 32 + lb * 8]);
      bf16x8 vf[4][2];
#pragma unroll
      for (int n = 0; n < 4; ++n) {
        const int row = n * 16 + lr;
#pragma unroll
        for (int ks = 0; ks < 2; ++ks)
          vf[n][ks] = *reinterpret_cast<const bf16x8*>(
              vbase + row * 128 + ((ks * 64 + lb * 16) ^ ((row & 7) << 4)));
      }

      __builtin_amdgcn_s_setprio(1);
#pragma unroll
      for (int m = 0; m < 2; ++m)
#pragma unroll
        for (int n = 0; n < 4; ++n) {
          o[m][n] = __builtin_amdgcn_mfma_f32_16x16x32_bf16(pa[m][0], vf[n][0], o[m][n], 0, 0, 0);
          o[m][n] = __builtin_amdgcn_mfma_f32_16x16x32_bf16(pa[m][1], vf[n][1], o[m][n], 0, 0, 0);
        }
      __builtin_amdgcn_s_setprio(0);
    }

    __syncthreads();  // staged tile t+1 visible; all waves advance together
  }

  // epilogue: normalize (lrun at q=lr; o rows at q=4lb+r -> shuffle), write
#pragma unroll
  for (int m = 0; m < 2; ++m)
#pragma unroll
    for (int r = 0; r < 4; ++r) {
      const float ln = __shfl(lrun[m], 4 * lb + r, 64);
      const float inv = 1.f / ln;
      const int q = q0 + m * 16 + 4 * lb + r;
#pragma unroll
      for (int n = 0; n < 4; ++n)
        AO[((size_t)(bb * S + q)) * D + h * DK + n * 16 + lr] = (__bf16)(o[m][n][r] * inv);
    }
}

// ---------------------------------------------------------------------------
// Kernel 3 (m97 structure): out = AO @ Wob^T, f32 output.
// ---------------------------------------------------------------------------
__global__ __launch_bounds__(256) void out_gemm(const __bf16* __restrict__ AOp,
                                                const __bf16* __restrict__ Wb,
                                                float* __restrict__ Out) {
  __shared__ __bf16 As[128 * 64];
  __shared__ __bf16 Bs[128 * 64];
  const int tid = threadIdx.x;
  const int lane = tid & 63;
  const int w = tid >> 6;
  const int wr = w >> 1, wc = w & 1;
  const int lr = lane & 15, lb = lane >> 4;
  const int m0 = blockIdx.x * 128, n0 = blockIdx.y * 128;

  int srow[4], sgcol[4];
#pragma unroll
  for (int rnd = 0; rnd < 4; ++rnd) {
    const int i = rnd * 256 + tid;
    srow[rnd] = i >> 3;
    sgcol[rnd] = ((i & 7) ^ (srow[rnd] & 7)) << 3;
  }

  f32x4 acc[4][4];
#pragma unroll
  for (int i = 0; i < 4; ++i)
#pragma unroll
    for (int j = 0; j < 4; ++j) acc[i][j] = f32x4{0.f, 0.f, 0.f, 0.f};

  for (int k0 = 0; k0 < D; k0 += 64) {
#pragma unroll
    for (int rnd = 0; rnd < 4; ++rnd) {
      GLOAD16(&AOp[(size_t)(m0 + srow[rnd]) * D + k0 + sgcol[rnd]],
              (char*)As + rnd * 4096 + w * 1024);
      GLOAD16(&Wb[(size_t)(n0 + srow[rnd]) * D + k0 + sgcol[rnd]],
              (char*)Bs + rnd * 4096 + w * 1024);
    }
    __syncthreads();

    bf16x8 af[4][2], bfr[4][2];
#pragma unroll
    for (int m = 0; m < 4; ++m) {
      const int row = wr * 64 + m * 16 + lr;
#pragma unroll
      for (int ks = 0; ks < 2; ++ks)
        af[m][ks] = *reinterpret_cast<const bf16x8*>(
            (const char*)As + row * 128 + (((ks * 32 + lb * 8) << 1) ^ ((row & 7) << 4)));
    }
#pragma unroll
    for (int n = 0; n < 4; ++n) {
      const int row = wc * 64 + n * 16 + lr;
#pragma unroll
      for (int ks = 0; ks < 2; ++ks)
        bfr[n][ks] = *reinterpret_cast<const bf16x8*>(
            (const char*)Bs + row * 128 + (((ks * 32 + lb * 8) << 1) ^ ((row & 7) << 4)));
    }
#pragma unroll
    for (int m = 0; m < 4; ++m)
#pragma unroll
      for (int n = 0; n < 4; ++n) {
        acc[m][n] = __builtin_amdgcn_mfma_f32_16x16x32_bf16(af[m][0], bfr[n][0], acc[m][n], 0, 0, 0);
        acc[m][n] = __builtin_amdgcn_mfma_f32_16x16x32_bf16(af[m][1], bfr[n][1], acc[m][n], 0, 0, 0);
      }
    __syncthreads();
  }

#pragma unroll
  for (int m = 0; m < 4; ++m)
#pragma unroll
    for (int n = 0; n < 4; ++n)
#pragma unroll
      for (int r = 0; r < 4; ++r)
        Out[(size_t)(m0 + wr * 64 + m * 16 + lb * 4 + r) * D + n0 + wc * 64 + n * 16 + lr] =
            acc[m][n][r];
}

// ---------------------------------------------------------------------------
extern "C" void kernel_launch(void* const* d_in, const int* in_sizes, int n_in,
                              void* d_out, int out_size, void* d_ws, size_t ws_size,
                              hipStream_t stream) {
  (void)in_sizes; (void)n_in; (void)out_size; (void)ws_size;
  const float* x = (const float*)d_in[0];
  // d_in[1] = causal mask — recomputed analytically, not read
  const float* w_qkv = (const float*)d_in[2];
  const float* b_qkv = (const float*)d_in[3];
  const float* w_o = (const float*)d_in[4];
  float* out = (float*)d_out;

  const size_t qkv_elems = (size_t)B * H * S * DK;  // 8,388,608 (= B*S*D)
  __bf16* Qb = (__bf16*)d_ws;
  __bf16* Kb = Qb + qkv_elems;
  __bf16* VTb = Kb + qkv_elems;
  __bf16* AO = VTb + qkv_elems;
  __bf16* Xb = AO + qkv_elems;
  __bf16* Wqkvb = Xb + (size_t)B * S * D;
  __bf16* Wob = Wqkvb + (size_t)3 * D * D;  // total ~92 MB of workspace

  convert_bf16<<<2048, 256, 0, stream>>>(x, w_qkv, w_o, Xb, Wqkvb, Wob);
  qkv_gemm<<<dim3(64, 24), 256, 0, stream>>>(Xb, Wqkvb, b_qkv, Qb, Kb, VTb);
  attn_fwd<<<dim3(8 * (B * H)), 512, 0, stream>>>(Qb, Kb, VTb, AO);
  out_gemm<<<dim3(64, 8), 256, 0, stream>>>(AO, Wob, out);
}

// Round 8
// 216.583 us; speedup vs baseline: 1.1924x; 1.1924x over previous
//
#include <hip/hip_runtime.h>
#include <hip/hip_bf16.h>

typedef __attribute__((ext_vector_type(8))) __bf16 bf16x8;
typedef __attribute__((ext_vector_type(4))) __bf16 bf16x4;
typedef __attribute__((ext_vector_type(4))) float f32x4;

constexpr int B = 4, S = 2048, D = 1024, H = 16, DK = 64;

#define GLOAD16(gp, lp)                                                              \
  __builtin_amdgcn_global_load_lds((const __attribute__((address_space(1))) void*)(gp), \
                                   (__attribute__((address_space(3))) void*)(lp), 16, 0, 0)

// ---------------------------------------------------------------------------
// Kernel 0: one-shot f32 -> bf16 conversion of X, w_qkv, w_o into workspace.
// ---------------------------------------------------------------------------
__global__ __launch_bounds__(256) void convert_bf16(const float* __restrict__ X,
                                                    const float* __restrict__ Wqkv,
                                                    const float* __restrict__ Wo,
                                                    __bf16* __restrict__ Xb,
                                                    __bf16* __restrict__ Wqkvb,
                                                    __bf16* __restrict__ Wob) {
  const int NX = B * S * D;
  const int NW = 3 * D * D;
  const int NO = D * D;
  const int total8 = (NX + NW + NO) / 8;
  for (int i = blockIdx.x * blockDim.x + threadIdx.x; i < total8;
       i += gridDim.x * blockDim.x) {
    const int e = i * 8;
    const float* src;
    __bf16* dst;
    int off;
    if (e < NX) {
      src = X; dst = Xb; off = e;
    } else if (e < NX + NW) {
      src = Wqkv; dst = Wqkvb; off = e - NX;
    } else {
      src = Wo; dst = Wob; off = e - NX - NW;
    }
    float4 a = *reinterpret_cast<const float4*>(src + off);
    float4 b = *reinterpret_cast<const float4*>(src + off + 4);
    bf16x8 v = {(__bf16)a.x, (__bf16)a.y, (__bf16)a.z, (__bf16)a.w,
                (__bf16)b.x, (__bf16)b.y, (__bf16)b.z, (__bf16)b.w};
    *reinterpret_cast<bf16x8*>(dst + off) = v;
  }
}

// ---------------------------------------------------------------------------
// Kernel 1 (m97 structure): qkv = Xb @ Wqkvb^T + b ; scatter to Q (scaled by
// 0.125*log2(e)), K, V^T, all bf16. 128x128 tile, BK=64, gload_lds staging.
// ---------------------------------------------------------------------------
__global__ __launch_bounds__(256) void qkv_gemm(const __bf16* __restrict__ Xb,
                                                const __bf16* __restrict__ Wb,
                                                const float* __restrict__ bias,
                                                __bf16* __restrict__ Qb,
                                                __bf16* __restrict__ Kb,
                                                __bf16* __restrict__ VTb) {
  __shared__ __bf16 As[128 * 64];
  __shared__ __bf16 Bs[128 * 64];
  const int tid = threadIdx.x;
  const int lane = tid & 63;
  const int w = tid >> 6;
  const int wr = w >> 1, wc = w & 1;
  const int lr = lane & 15, lb = lane >> 4;
  const int m0 = blockIdx.x * 128, n0 = blockIdx.y * 128;

  int srow[4], sgcol[4];
#pragma unroll
  for (int rnd = 0; rnd < 4; ++rnd) {
    const int i = rnd * 256 + tid;
    srow[rnd] = i >> 3;
    sgcol[rnd] = ((i & 7) ^ (srow[rnd] & 7)) << 3;
  }

  f32x4 acc[4][4];
#pragma unroll
  for (int i = 0; i < 4; ++i)
#pragma unroll
    for (int j = 0; j < 4; ++j) acc[i][j] = f32x4{0.f, 0.f, 0.f, 0.f};

  for (int k0 = 0; k0 < D; k0 += 64) {
#pragma unroll
    for (int rnd = 0; rnd < 4; ++rnd) {
      GLOAD16(&Xb[(size_t)(m0 + srow[rnd]) * D + k0 + sgcol[rnd]],
              (char*)As + rnd * 4096 + w * 1024);
      GLOAD16(&Wb[(size_t)(n0 + srow[rnd]) * D + k0 + sgcol[rnd]],
              (char*)Bs + rnd * 4096 + w * 1024);
    }
    __syncthreads();

    bf16x8 af[4][2], bfr[4][2];
#pragma unroll
    for (int m = 0; m < 4; ++m) {
      const int row = wr * 64 + m * 16 + lr;
#pragma unroll
      for (int ks = 0; ks < 2; ++ks)
        af[m][ks] = *reinterpret_cast<const bf16x8*>(
            (const char*)As + row * 128 + (((ks * 32 + lb * 8) << 1) ^ ((row & 7) << 4)));
    }
#pragma unroll
    for (int n = 0; n < 4; ++n) {
      const int row = wc * 64 + n * 16 + lr;
#pragma unroll
      for (int ks = 0; ks < 2; ++ks)
        bfr[n][ks] = *reinterpret_cast<const bf16x8*>(
            (const char*)Bs + row * 128 + (((ks * 32 + lb * 8) << 1) ^ ((row & 7) << 4)));
    }
#pragma unroll
    for (int m = 0; m < 4; ++m)
#pragma unroll
      for (int n = 0; n < 4; ++n) {
        acc[m][n] = __builtin_amdgcn_mfma_f32_16x16x32_bf16(af[m][0], bfr[n][0], acc[m][n], 0, 0, 0);
        acc[m][n] = __builtin_amdgcn_mfma_f32_16x16x32_bf16(af[m][1], bfr[n][1], acc[m][n], 0, 0, 0);
      }
    __syncthreads();
  }

  const int seg = n0 >> 10;
#pragma unroll
  for (int m = 0; m < 4; ++m)
#pragma unroll
    for (int n = 0; n < 4; ++n) {
      const int c = n0 + wc * 64 + n * 16 + lr;
      const int cc = c & 1023;
      const int h = cc >> 6, dk = cc & 63;
      const float bv = bias[c];
#pragma unroll
      for (int r = 0; r < 4; ++r) {
        const int t = m0 + wr * 64 + m * 16 + lb * 4 + r;
        const int bb = t >> 11;
        const int s = t & 2047;
        const float v = acc[m][n][r] + bv;
        const size_t bh = (size_t)bb * H + h;
        if (seg == 0)
          Qb[(bh * S + s) * DK + dk] = (__bf16)(v * 0.180336893f);  // 0.125*log2(e)
        else if (seg == 1)
          Kb[(bh * S + s) * DK + dk] = (__bf16)v;
        else
          VTb[(bh * DK + dk) * S + s] = (__bf16)v;
      }
    }
}

// ---------------------------------------------------------------------------
// Kernel 2 (round 7): round-5 schedule + single-buffer K/V + balanced decode.
// 4 waves/block (256 thr), wave w owns q-rows [qt*128+w*32, +32); KVBLK=64.
// Grid 1024 (all resident: LDS 34KB -> 4 blocks/CU). Decode: xcd=flat&7,
// idx=flat>>3, hg=idx&7, qpart=idx>>3, u=qpart&3, v=qpart>>2,
// qt = 4v + (v odd ? 3-u : u)  -> under round-robin dispatch each CU's four
// blocks {c,c+256,c+512,c+768} have qt summing to 30 (uniform 68 tile-units
// per CU); bh = hg*8+xcd keeps each head's K/V on one XCD's L2.
// T14 reg-staged pipeline: issue t+1 global loads -> compute t from LDS ->
// barrier -> ds_write t+1 (same buffer) -> barrier.
// Swapped QK^T; exp2-domain softmax; defer-max THR=11; XOR-swizzled K/V LDS.
// ---------------------------------------------------------------------------
__global__ __launch_bounds__(256) void attn_fwd(const __bf16* __restrict__ Qb,
                                                const __bf16* __restrict__ Kb,
                                                const __bf16* __restrict__ VTb,
                                                __bf16* __restrict__ AO) {
  __shared__ __bf16 Kl[64 * 64];
  __shared__ __bf16 Vl[64 * 64];
  __shared__ __bf16 Ps[4][32][72];
  const int tid = threadIdx.x;
  const int lane = tid & 63;
  const int w = tid >> 6;
  const int lr = lane & 15, lb = lane >> 4;

  const int flat = blockIdx.x;
  const int xcd = flat & 7;
  const int idx = flat >> 3;
  const int hg = idx & 7;
  const int qpart = idx >> 3;
  const int u = qpart & 3, v = qpart >> 2;
  const int qt = 4 * v + ((v & 1) ? (3 - u) : u);
  const int bh = hg * 8 + xcd;
  const int q0 = qt * 128 + w * 32;
  const int bb = bh >> 4, h = bh & 15;

  const __bf16* Q = Qb + (size_t)bh * S * DK;
  const __bf16* K = Kb + (size_t)bh * S * DK;
  const __bf16* VT = VTb + (size_t)bh * DK * S;

  const int nt = 2 * qt + 2;
  const int ntw = 2 * qt + 1 + (w >> 1);

  const int srow = tid >> 2;
  const int scol = (tid & 3) * 16;
  const int sbyte = srow * 128 + scol * 2;
  const int sswz = (srow & 7) << 4;

  bf16x8 qf[2][2];
#pragma unroll
  for (int m = 0; m < 2; ++m)
#pragma unroll
    for (int d = 0; d < 2; ++d)
      qf[m][d] = *reinterpret_cast<const bf16x8*>(
          &Q[(size_t)(q0 + m * 16 + lr) * DK + d * 32 + lb * 8]);

  // prologue: stage tile 0
  {
    const __bf16* Kg = K + (size_t)srow * DK + scol;
    bf16x8 k0 = *reinterpret_cast<const bf16x8*>(Kg);
    bf16x8 k1 = *reinterpret_cast<const bf16x8*>(Kg + 8);
    const __bf16* Vg = VT + (size_t)srow * S + scol;
    bf16x8 v0 = *reinterpret_cast<const bf16x8*>(Vg);
    bf16x8 v1 = *reinterpret_cast<const bf16x8*>(Vg + 8);
    char* kd = (char*)&Kl[0];
    char* vd = (char*)&Vl[0];
    *reinterpret_cast<bf16x8*>(kd + (sbyte ^ sswz)) = k0;
    *reinterpret_cast<bf16x8*>(kd + ((sbyte + 16) ^ sswz)) = k1;
    *reinterpret_cast<bf16x8*>(vd + (sbyte ^ sswz)) = v0;
    *reinterpret_cast<bf16x8*>(vd + ((sbyte + 16) ^ sswz)) = v1;
  }
  __syncthreads();

  f32x4 o[2][4];
#pragma unroll
  for (int m = 0; m < 2; ++m)
#pragma unroll
    for (int n = 0; n < 4; ++n) o[m][n] = f32x4{0.f, 0.f, 0.f, 0.f};
  float mrun[2], lrun[2];
#pragma unroll
  for (int m = 0; m < 2; ++m) {
    mrun[m] = -1e30f;
    lrun[m] = 0.f;
  }

  for (int t = 0; t < nt; ++t) {
    const int kv0 = t * 64;
    const bool have_next = (t + 1 < nt);
    bf16x8 gk0, gk1, gv0, gv1;
    if (have_next) {  // issue next-tile loads early; latency hides under compute
      const __bf16* Kg = K + ((size_t)(kv0 + 64) + srow) * DK + scol;
      gk0 = *reinterpret_cast<const bf16x8*>(Kg);
      gk1 = *reinterpret_cast<const bf16x8*>(Kg + 8);
      const __bf16* Vg = VT + (size_t)srow * S + (kv0 + 64) + scol;
      gv0 = *reinterpret_cast<const bf16x8*>(Vg);
      gv1 = *reinterpret_cast<const bf16x8*>(Vg + 8);
    }

    if (t < ntw) {
      const char* kbase = (const char*)&Kl[0];
      const char* vbase = (const char*)&Vl[0];
      const int rsw = (lr & 7) << 4;
      bf16x8 kf[4][2];
#pragma unroll
      for (int kc = 0; kc < 4; ++kc)
#pragma unroll
        for (int d = 0; d < 2; ++d)
          kf[kc][d] = *reinterpret_cast<const bf16x8*>(
              kbase + (kc * 16 + lr) * 128 + ((d * 64 + lb * 16) ^ rsw));

      // swapped QK^T: st[m][kc][r] = S^T[k=kv0+kc*16+4lb+r][q=q0+m*16+lr]
      f32x4 st[2][4];
      __builtin_amdgcn_s_setprio(1);
#pragma unroll
      for (int m = 0; m < 2; ++m)
#pragma unroll
        for (int kc = 0; kc < 4; ++kc) {
          f32x4 z = f32x4{0.f, 0.f, 0.f, 0.f};
          z = __builtin_amdgcn_mfma_f32_16x16x32_bf16(kf[kc][0], qf[m][0], z, 0, 0, 0);
          z = __builtin_amdgcn_mfma_f32_16x16x32_bf16(kf[kc][1], qf[m][1], z, 0, 0, 0);
          st[m][kc] = z;
        }
      __builtin_amdgcn_s_setprio(0);

      if (t == ntw - 1) {  // diagonal tile: mask k > q
#pragma unroll
        for (int m = 0; m < 2; ++m) {
          const int qg = q0 + m * 16 + lr;
#pragma unroll
          for (int kc = 0; kc < 4; ++kc)
#pragma unroll
            for (int r = 0; r < 4; ++r) {
              const int kg = kv0 + kc * 16 + 4 * lb + r;
              if (kg > qg) st[m][kc][r] = -1e30f;
            }
        }
      }

#pragma unroll
      for (int m = 0; m < 2; ++m) {
        float mx = st[m][0][0];
#pragma unroll
        for (int kc = 0; kc < 4; ++kc)
#pragma unroll
          for (int r = 0; r < 4; ++r) mx = fmaxf(mx, st[m][kc][r]);
        mx = fmaxf(mx, __shfl_xor(mx, 16, 64));
        mx = fmaxf(mx, __shfl_xor(mx, 32, 64));

        if (__any(mx > mrun[m] + 11.f)) {  // defer-max (exp2 domain)
          const float nm = fmaxf(mrun[m], mx);
          const float alpha = exp2f(mrun[m] - nm);
          mrun[m] = nm;
          lrun[m] *= alpha;
#pragma unroll
          for (int r = 0; r < 4; ++r) {
            const float ao = __shfl(alpha, 4 * lb + r, 64);
#pragma unroll
            for (int n = 0; n < 4; ++n) o[m][n][r] *= ao;
          }
        }

        float rs = 0.f;
#pragma unroll
        for (int kc = 0; kc < 4; ++kc) {
          bf16x4 pk;
#pragma unroll
          for (int r = 0; r < 4; ++r) {
            const float p = exp2f(st[m][kc][r] - mrun[m]);
            rs += p;
            pk[r] = (__bf16)p;
          }
          *reinterpret_cast<bf16x4*>(&Ps[w][m * 16 + lr][kc * 16 + 4 * lb]) = pk;
        }
        rs += __shfl_xor(rs, 16, 64);
        rs += __shfl_xor(rs, 32, 64);
        lrun[m] += rs;
      }

      asm volatile("s_waitcnt lgkmcnt(0)" ::: "memory");
      __builtin_amdgcn_sched_barrier(0);

      bf16x8 pa[2][2];
#pragma unroll
      for (int m = 0; m < 2; ++m)
#pragma unroll
        for (int ks = 0; ks < 2; ++ks)
          pa[m][ks] = *reinterpret_cast<const bf16x8*>(&Ps[w][m * 16 + lr][ks * 32 + lb * 8]);
      bf16x8 vf[4][2];
#pragma unroll
      for (int n = 0; n < 4; ++n)
#pragma unroll
        for (int ks = 0; ks < 2; ++ks)
          vf[n][ks] = *reinterpret_cast<const bf16x8*>(
              vbase + (n * 16 + lr) * 128 + ((ks * 64 + lb * 16) ^ rsw));

      __builtin_amdgcn_s_setprio(1);
#pragma unroll
      for (int m = 0; m < 2; ++m)
#pragma unroll
        for (int n = 0; n < 4; ++n) {
          o[m][n] = __builtin_amdgcn_mfma_f32_16x16x32_bf16(pa[m][0], vf[n][0], o[m][n], 0, 0, 0);
          o[m][n] = __builtin_amdgcn_mfma_f32_16x16x32_bf16(pa[m][1], vf[n][1], o[m][n], 0, 0, 0);
        }
      __builtin_amdgcn_s_setprio(0);
    }

    __syncthreads();  // all waves done reading Kl/Vl for tile t
    if (have_next) {  // overwrite the single buffer with tile t+1
      char* kd = (char*)&Kl[0];
      char* vd = (char*)&Vl[0];
      *reinterpret_cast<bf16x8*>(kd + (sbyte ^ sswz)) = gk0;
      *reinterpret_cast<bf16x8*>(kd + ((sbyte + 16) ^ sswz)) = gk1;
      *reinterpret_cast<bf16x8*>(vd + (sbyte ^ sswz)) = gv0;
      *reinterpret_cast<bf16x8*>(vd + ((sbyte + 16) ^ sswz)) = gv1;
    }
    __syncthreads();  // staged tile visible before next compute
  }

  // epilogue: normalize (lrun at q=lr; o rows at q=4lb+r -> shuffle), write
#pragma unroll
  for (int m = 0; m < 2; ++m)
#pragma unroll
    for (int r = 0; r < 4; ++r) {
      const float ln = __shfl(lrun[m], 4 * lb + r, 64);
      const float inv = 1.f / ln;
      const int q = q0 + m * 16 + 4 * lb + r;
#pragma unroll
      for (int n = 0; n < 4; ++n)
        AO[((size_t)(bb * S + q)) * D + h * DK + n * 16 + lr] = (__bf16)(o[m][n][r] * inv);
    }
}

// ---------------------------------------------------------------------------
// Kernel 3 (m97 structure): out = AO @ Wob^T, f32 output.
// ---------------------------------------------------------------------------
__global__ __launch_bounds__(256) void out_gemm(const __bf16* __restrict__ AOp,
                                                const __bf16* __restrict__ Wb,
                                                float* __restrict__ Out) {
  __shared__ __bf16 As[128 * 64];
  __shared__ __bf16 Bs[128 * 64];
  const int tid = threadIdx.x;
  const int lane = tid & 63;
  const int w = tid >> 6;
  const int wr = w >> 1, wc = w & 1;
  const int lr = lane & 15, lb = lane >> 4;
  const int m0 = blockIdx.x * 128, n0 = blockIdx.y * 128;

  int srow[4], sgcol[4];
#pragma unroll
  for (int rnd = 0; rnd < 4; ++rnd) {
    const int i = rnd * 256 + tid;
    srow[rnd] = i >> 3;
    sgcol[rnd] = ((i & 7) ^ (srow[rnd] & 7)) << 3;
  }

  f32x4 acc[4][4];
#pragma unroll
  for (int i = 0; i < 4; ++i)
#pragma unroll
    for (int j = 0; j < 4; ++j) acc[i][j] = f32x4{0.f, 0.f, 0.f, 0.f};

  for (int k0 = 0; k0 < D; k0 += 64) {
#pragma unroll
    for (int rnd = 0; rnd < 4; ++rnd) {
      GLOAD16(&AOp[(size_t)(m0 + srow[rnd]) * D + k0 + sgcol[rnd]],
              (char*)As + rnd * 4096 + w * 1024);
      GLOAD16(&Wb[(size_t)(n0 + srow[rnd]) * D + k0 + sgcol[rnd]],
              (char*)Bs + rnd * 4096 + w * 1024);
    }
    __syncthreads();

    bf16x8 af[4][2], bfr[4][2];
#pragma unroll
    for (int m = 0; m < 4; ++m) {
      const int row = wr * 64 + m * 16 + lr;
#pragma unroll
      for (int ks = 0; ks < 2; ++ks)
        af[m][ks] = *reinterpret_cast<const bf16x8*>(
            (const char*)As + row * 128 + (((ks * 32 + lb * 8) << 1) ^ ((row & 7) << 4)));
    }
#pragma unroll
    for (int n = 0; n < 4; ++n) {
      const int row = wc * 64 + n * 16 + lr;
#pragma unroll
      for (int ks = 0; ks < 2; ++ks)
        bfr[n][ks] = *reinterpret_cast<const bf16x8*>(
            (const char*)Bs + row * 128 + (((ks * 32 + lb * 8) << 1) ^ ((row & 7) << 4)));
    }
#pragma unroll
    for (int m = 0; m < 4; ++m)
#pragma unroll
      for (int n = 0; n < 4; ++n) {
        acc[m][n] = __builtin_amdgcn_mfma_f32_16x16x32_bf16(af[m][0], bfr[n][0], acc[m][n], 0, 0, 0);
        acc[m][n] = __builtin_amdgcn_mfma_f32_16x16x32_bf16(af[m][1], bfr[n][1], acc[m][n], 0, 0, 0);
      }
    __syncthreads();
  }

#pragma unroll
  for (int m = 0; m < 4; ++m)
#pragma unroll
    for (int n = 0; n < 4; ++n)
#pragma unroll
      for (int r = 0; r < 4; ++r)
        Out[(size_t)(m0 + wr * 64 + m * 16 + lb * 4 + r) * D + n0 + wc * 64 + n * 16 + lr] =
            acc[m][n][r];
}

// ---------------------------------------------------------------------------
extern "C" void kernel_launch(void* const* d_in, const int* in_sizes, int n_in,
                              void* d_out, int out_size, void* d_ws, size_t ws_size,
                              hipStream_t stream) {
  (void)in_sizes; (void)n_in; (void)out_size; (void)ws_size;
  const float* x = (const float*)d_in[0];
  // d_in[1] = causal mask — recomputed analytically, not read
  const float* w_qkv = (const float*)d_in[2];
  const float* b_qkv = (const float*)d_in[3];
  const float* w_o = (const float*)d_in[4];
  float* out = (float*)d_out;

  const size_t qkv_elems = (size_t)B * H * S * DK;  // 8,388,608 (= B*S*D)
  __bf16* Qb = (__bf16*)d_ws;
  __bf16* Kb = Qb + qkv_elems;
  __bf16* VTb = Kb + qkv_elems;
  __bf16* AO = VTb + qkv_elems;
  __bf16* Xb = AO + qkv_elems;
  __bf16* Wqkvb = Xb + (size_t)B * S * D;
  __bf16* Wob = Wqkvb + (size_t)3 * D * D;  // total ~92 MB of workspace

  convert_bf16<<<2048, 256, 0, stream>>>(x, w_qkv, w_o, Xb, Wqkvb, Wob);
  qkv_gemm<<<dim3(64, 24), 256, 0, stream>>>(Xb, Wqkvb, b_qkv, Qb, Kb, VTb);
  attn_fwd<<<dim3((S / 128) * (B * H)), 256, 0, stream>>>(Qb, Kb, VTb, AO);
  out_gemm<<<dim3(64, 8), 256, 0, stream>>>(AO, Wob, out);
}

// Round 9
// 203.732 us; speedup vs baseline: 1.2676x; 1.0631x over previous
//
#include <hip/hip_runtime.h>
#include <hip/hip_bf16.h>

typedef __attribute__((ext_vector_type(8))) __bf16 bf16x8;
typedef __attribute__((ext_vector_type(4))) __bf16 bf16x4;
typedef __attribute__((ext_vector_type(4))) float f32x4;

constexpr int B = 4, S = 2048, D = 1024, H = 16, DK = 64;

#define GLOAD16(gp, lp)                                                              \
  __builtin_amdgcn_global_load_lds((const __attribute__((address_space(1))) void*)(gp), \
                                   (__attribute__((address_space(3))) void*)(lp), 16, 0, 0)

// ---------------------------------------------------------------------------
// Kernel 0: one-shot f32 -> bf16 conversion of X, w_qkv, w_o into workspace.
// ---------------------------------------------------------------------------
__global__ __launch_bounds__(256) void convert_bf16(const float* __restrict__ X,
                                                    const float* __restrict__ Wqkv,
                                                    const float* __restrict__ Wo,
                                                    __bf16* __restrict__ Xb,
                                                    __bf16* __restrict__ Wqkvb,
                                                    __bf16* __restrict__ Wob) {
  const int NX = B * S * D;
  const int NW = 3 * D * D;
  const int NO = D * D;
  const int total8 = (NX + NW + NO) / 8;
  for (int i = blockIdx.x * blockDim.x + threadIdx.x; i < total8;
       i += gridDim.x * blockDim.x) {
    const int e = i * 8;
    const float* src;
    __bf16* dst;
    int off;
    if (e < NX) {
      src = X; dst = Xb; off = e;
    } else if (e < NX + NW) {
      src = Wqkv; dst = Wqkvb; off = e - NX;
    } else {
      src = Wo; dst = Wob; off = e - NX - NW;
    }
    float4 a = *reinterpret_cast<const float4*>(src + off);
    float4 b = *reinterpret_cast<const float4*>(src + off + 4);
    bf16x8 v = {(__bf16)a.x, (__bf16)a.y, (__bf16)a.z, (__bf16)a.w,
                (__bf16)b.x, (__bf16)b.y, (__bf16)b.z, (__bf16)b.w};
    *reinterpret_cast<bf16x8*>(dst + off) = v;
  }
}

// ---------------------------------------------------------------------------
// Kernel 1 (m97 structure): qkv = Xb @ Wqkvb^T + b ; scatter to Q (scaled by
// 0.125*log2(e)), K, V^T, all bf16. 128x128 tile, BK=64, gload_lds staging.
// ---------------------------------------------------------------------------
__global__ __launch_bounds__(256) void qkv_gemm(const __bf16* __restrict__ Xb,
                                                const __bf16* __restrict__ Wb,
                                                const float* __restrict__ bias,
                                                __bf16* __restrict__ Qb,
                                                __bf16* __restrict__ Kb,
                                                __bf16* __restrict__ VTb) {
  __shared__ __bf16 As[128 * 64];
  __shared__ __bf16 Bs[128 * 64];
  const int tid = threadIdx.x;
  const int lane = tid & 63;
  const int w = tid >> 6;
  const int wr = w >> 1, wc = w & 1;
  const int lr = lane & 15, lb = lane >> 4;
  const int m0 = blockIdx.x * 128, n0 = blockIdx.y * 128;

  int srow[4], sgcol[4];
#pragma unroll
  for (int rnd = 0; rnd < 4; ++rnd) {
    const int i = rnd * 256 + tid;
    srow[rnd] = i >> 3;
    sgcol[rnd] = ((i & 7) ^ (srow[rnd] & 7)) << 3;
  }

  f32x4 acc[4][4];
#pragma unroll
  for (int i = 0; i < 4; ++i)
#pragma unroll
    for (int j = 0; j < 4; ++j) acc[i][j] = f32x4{0.f, 0.f, 0.f, 0.f};

  for (int k0 = 0; k0 < D; k0 += 64) {
#pragma unroll
    for (int rnd = 0; rnd < 4; ++rnd) {
      GLOAD16(&Xb[(size_t)(m0 + srow[rnd]) * D + k0 + sgcol[rnd]],
              (char*)As + rnd * 4096 + w * 1024);
      GLOAD16(&Wb[(size_t)(n0 + srow[rnd]) * D + k0 + sgcol[rnd]],
              (char*)Bs + rnd * 4096 + w * 1024);
    }
    __syncthreads();

    bf16x8 af[4][2], bfr[4][2];
#pragma unroll
    for (int m = 0; m < 4; ++m) {
      const int row = wr * 64 + m * 16 + lr;
#pragma unroll
      for (int ks = 0; ks < 2; ++ks)
        af[m][ks] = *reinterpret_cast<const bf16x8*>(
            (const char*)As + row * 128 + (((ks * 32 + lb * 8) << 1) ^ ((row & 7) << 4)));
    }
#pragma unroll
    for (int n = 0; n < 4; ++n) {
      const int row = wc * 64 + n * 16 + lr;
#pragma unroll
      for (int ks = 0; ks < 2; ++ks)
        bfr[n][ks] = *reinterpret_cast<const bf16x8*>(
            (const char*)Bs + row * 128 + (((ks * 32 + lb * 8) << 1) ^ ((row & 7) << 4)));
    }
#pragma unroll
    for (int m = 0; m < 4; ++m)
#pragma unroll
      for (int n = 0; n < 4; ++n) {
        acc[m][n] = __builtin_amdgcn_mfma_f32_16x16x32_bf16(af[m][0], bfr[n][0], acc[m][n], 0, 0, 0);
        acc[m][n] = __builtin_amdgcn_mfma_f32_16x16x32_bf16(af[m][1], bfr[n][1], acc[m][n], 0, 0, 0);
      }
    __syncthreads();
  }

  const int seg = n0 >> 10;
#pragma unroll
  for (int m = 0; m < 4; ++m)
#pragma unroll
    for (int n = 0; n < 4; ++n) {
      const int c = n0 + wc * 64 + n * 16 + lr;
      const int cc = c & 1023;
      const int h = cc >> 6, dk = cc & 63;
      const float bv = bias[c];
#pragma unroll
      for (int r = 0; r < 4; ++r) {
        const int t = m0 + wr * 64 + m * 16 + lb * 4 + r;
        const int bb = t >> 11;
        const int s = t & 2047;
        const float v = acc[m][n][r] + bv;
        const size_t bh = (size_t)bb * H + h;
        if (seg == 0)
          Qb[(bh * S + s) * DK + dk] = (__bf16)(v * 0.180336893f);  // 0.125*log2(e)
        else if (seg == 1)
          Kb[(bh * S + s) * DK + dk] = (__bf16)v;
        else
          VTb[(bh * DK + dk) * S + s] = (__bf16)v;
      }
    }
}

// ---------------------------------------------------------------------------
// Kernel 2 (round 8): paired-q-tile causal flash attention, uniform makespan.
// Each block sequentially processes q-tiles qt=pr and qt=15-pr: trip count
// (2*pr+2)+(2*(15-pr)+2) = 34 for EVERY block -> zero tail drain, steady
// 2 blocks/CU x 4 waves. Grid 512: xcd=flat&7, idx=flat>>3, hg=idx&7,
// pr=idx>>3; bh=hg*8+xcd (head->XCD L2 locality, 8 heads/XCD).
// Inner kv loop identical to round 7: 4 waves, KVBLK=64, single-buffer K/V
// (XOR-swizzled), T14 reg-staged pipeline (issue t+1 loads -> compute t ->
// barrier -> ds_write -> barrier), swapped QK^T, exp2 softmax, defer-max 11.
// ---------------------------------------------------------------------------
__global__ __launch_bounds__(256) void attn_fwd(const __bf16* __restrict__ Qb,
                                                const __bf16* __restrict__ Kb,
                                                const __bf16* __restrict__ VTb,
                                                __bf16* __restrict__ AO) {
  __shared__ __bf16 Kl[64 * 64];
  __shared__ __bf16 Vl[64 * 64];
  __shared__ __bf16 Ps[4][32][72];
  const int tid = threadIdx.x;
  const int lane = tid & 63;
  const int w = tid >> 6;
  const int lr = lane & 15, lb = lane >> 4;

  const int flat = blockIdx.x;
  const int xcd = flat & 7;
  const int idx = flat >> 3;
  const int hg = idx & 7;
  const int pr = idx >> 3;  // 0..7 -> pair (pr, 15-pr)
  const int bh = hg * 8 + xcd;
  const int bb = bh >> 4, h = bh & 15;

  const __bf16* Q = Qb + (size_t)bh * S * DK;
  const __bf16* K = Kb + (size_t)bh * S * DK;
  const __bf16* VT = VTb + (size_t)bh * DK * S;

  const int srow = tid >> 2;
  const int scol = (tid & 3) * 16;
  const int sbyte = srow * 128 + scol * 2;
  const int sswz = (srow & 7) << 4;

  for (int pass = 0; pass < 2; ++pass) {
    const int qt = pass ? (15 - pr) : pr;
    const int q0 = qt * 128 + w * 32;
    const int nt = 2 * qt + 2;
    const int ntw = 2 * qt + 1 + (w >> 1);

    bf16x8 qf[2][2];
#pragma unroll
    for (int m = 0; m < 2; ++m)
#pragma unroll
      for (int d = 0; d < 2; ++d)
        qf[m][d] = *reinterpret_cast<const bf16x8*>(
            &Q[(size_t)(q0 + m * 16 + lr) * DK + d * 32 + lb * 8]);

    // prologue: stage tile 0 (safe: all pass-A LDS reads ended at its final barrier)
    {
      const __bf16* Kg = K + (size_t)srow * DK + scol;
      bf16x8 k0 = *reinterpret_cast<const bf16x8*>(Kg);
      bf16x8 k1 = *reinterpret_cast<const bf16x8*>(Kg + 8);
      const __bf16* Vg = VT + (size_t)srow * S + scol;
      bf16x8 v0 = *reinterpret_cast<const bf16x8*>(Vg);
      bf16x8 v1 = *reinterpret_cast<const bf16x8*>(Vg + 8);
      char* kd = (char*)&Kl[0];
      char* vd = (char*)&Vl[0];
      *reinterpret_cast<bf16x8*>(kd + (sbyte ^ sswz)) = k0;
      *reinterpret_cast<bf16x8*>(kd + ((sbyte + 16) ^ sswz)) = k1;
      *reinterpret_cast<bf16x8*>(vd + (sbyte ^ sswz)) = v0;
      *reinterpret_cast<bf16x8*>(vd + ((sbyte + 16) ^ sswz)) = v1;
    }
    __syncthreads();

    f32x4 o[2][4];
#pragma unroll
    for (int m = 0; m < 2; ++m)
#pragma unroll
      for (int n = 0; n < 4; ++n) o[m][n] = f32x4{0.f, 0.f, 0.f, 0.f};
    float mrun[2], lrun[2];
#pragma unroll
    for (int m = 0; m < 2; ++m) {
      mrun[m] = -1e30f;
      lrun[m] = 0.f;
    }

    for (int t = 0; t < nt; ++t) {
      const int kv0 = t * 64;
      const bool have_next = (t + 1 < nt);
      bf16x8 gk0, gk1, gv0, gv1;
      if (have_next) {  // issue next-tile loads early; latency hides under compute
        const __bf16* Kg = K + ((size_t)(kv0 + 64) + srow) * DK + scol;
        gk0 = *reinterpret_cast<const bf16x8*>(Kg);
        gk1 = *reinterpret_cast<const bf16x8*>(Kg + 8);
        const __bf16* Vg = VT + (size_t)srow * S + (kv0 + 64) + scol;
        gv0 = *reinterpret_cast<const bf16x8*>(Vg);
        gv1 = *reinterpret_cast<const bf16x8*>(Vg + 8);
      }

      if (t < ntw) {
        const char* kbase = (const char*)&Kl[0];
        const char* vbase = (const char*)&Vl[0];
        const int rsw = (lr & 7) << 4;
        bf16x8 kf[4][2];
#pragma unroll
        for (int kc = 0; kc < 4; ++kc)
#pragma unroll
          for (int d = 0; d < 2; ++d)
            kf[kc][d] = *reinterpret_cast<const bf16x8*>(
                kbase + (kc * 16 + lr) * 128 + ((d * 64 + lb * 16) ^ rsw));

        // swapped QK^T: st[m][kc][r] = S^T[k=kv0+kc*16+4lb+r][q=q0+m*16+lr]
        f32x4 st[2][4];
        __builtin_amdgcn_s_setprio(1);
#pragma unroll
        for (int m = 0; m < 2; ++m)
#pragma unroll
          for (int kc = 0; kc < 4; ++kc) {
            f32x4 z = f32x4{0.f, 0.f, 0.f, 0.f};
            z = __builtin_amdgcn_mfma_f32_16x16x32_bf16(kf[kc][0], qf[m][0], z, 0, 0, 0);
            z = __builtin_amdgcn_mfma_f32_16x16x32_bf16(kf[kc][1], qf[m][1], z, 0, 0, 0);
            st[m][kc] = z;
          }
        __builtin_amdgcn_s_setprio(0);

        if (t == ntw - 1) {  // diagonal tile: mask k > q
#pragma unroll
          for (int m = 0; m < 2; ++m) {
            const int qg = q0 + m * 16 + lr;
#pragma unroll
            for (int kc = 0; kc < 4; ++kc)
#pragma unroll
              for (int r = 0; r < 4; ++r) {
                const int kg = kv0 + kc * 16 + 4 * lb + r;
                if (kg > qg) st[m][kc][r] = -1e30f;
              }
          }
        }

#pragma unroll
        for (int m = 0; m < 2; ++m) {
          float mx = st[m][0][0];
#pragma unroll
          for (int kc = 0; kc < 4; ++kc)
#pragma unroll
            for (int r = 0; r < 4; ++r) mx = fmaxf(mx, st[m][kc][r]);
          mx = fmaxf(mx, __shfl_xor(mx, 16, 64));
          mx = fmaxf(mx, __shfl_xor(mx, 32, 64));

          if (__any(mx > mrun[m] + 11.f)) {  // defer-max (exp2 domain)
            const float nm = fmaxf(mrun[m], mx);
            const float alpha = exp2f(mrun[m] - nm);
            mrun[m] = nm;
            lrun[m] *= alpha;
#pragma unroll
            for (int r = 0; r < 4; ++r) {
              const float ao = __shfl(alpha, 4 * lb + r, 64);
#pragma unroll
              for (int n = 0; n < 4; ++n) o[m][n][r] *= ao;
            }
          }

          float rs = 0.f;
#pragma unroll
          for (int kc = 0; kc < 4; ++kc) {
            bf16x4 pk;
#pragma unroll
            for (int r = 0; r < 4; ++r) {
              const float p = exp2f(st[m][kc][r] - mrun[m]);
              rs += p;
              pk[r] = (__bf16)p;
            }
            *reinterpret_cast<bf16x4*>(&Ps[w][m * 16 + lr][kc * 16 + 4 * lb]) = pk;
          }
          rs += __shfl_xor(rs, 16, 64);
          rs += __shfl_xor(rs, 32, 64);
          lrun[m] += rs;
        }

        asm volatile("s_waitcnt lgkmcnt(0)" ::: "memory");
        __builtin_amdgcn_sched_barrier(0);

        bf16x8 pa[2][2];
#pragma unroll
        for (int m = 0; m < 2; ++m)
#pragma unroll
          for (int ks = 0; ks < 2; ++ks)
            pa[m][ks] = *reinterpret_cast<const bf16x8*>(&Ps[w][m * 16 + lr][ks * 32 + lb * 8]);
        bf16x8 vf[4][2];
#pragma unroll
        for (int n = 0; n < 4; ++n)
#pragma unroll
          for (int ks = 0; ks < 2; ++ks)
            vf[n][ks] = *reinterpret_cast<const bf16x8*>(
                vbase + (n * 16 + lr) * 128 + ((ks * 64 + lb * 16) ^ rsw));

        __builtin_amdgcn_s_setprio(1);
#pragma unroll
        for (int m = 0; m < 2; ++m)
#pragma unroll
          for (int n = 0; n < 4; ++n) {
            o[m][n] = __builtin_amdgcn_mfma_f32_16x16x32_bf16(pa[m][0], vf[n][0], o[m][n], 0, 0, 0);
            o[m][n] = __builtin_amdgcn_mfma_f32_16x16x32_bf16(pa[m][1], vf[n][1], o[m][n], 0, 0, 0);
          }
        __builtin_amdgcn_s_setprio(0);
      }

      __syncthreads();  // all waves done reading Kl/Vl for tile t
      if (have_next) {  // overwrite the single buffer with tile t+1
        char* kd = (char*)&Kl[0];
        char* vd = (char*)&Vl[0];
        *reinterpret_cast<bf16x8*>(kd + (sbyte ^ sswz)) = gk0;
        *reinterpret_cast<bf16x8*>(kd + ((sbyte + 16) ^ sswz)) = gk1;
        *reinterpret_cast<bf16x8*>(vd + (sbyte ^ sswz)) = gv0;
        *reinterpret_cast<bf16x8*>(vd + ((sbyte + 16) ^ sswz)) = gv1;
      }
      __syncthreads();  // staged tile visible before next compute
    }

    // epilogue: normalize (lrun at q=lr; o rows at q=4lb+r -> shuffle), write
#pragma unroll
    for (int m = 0; m < 2; ++m)
#pragma unroll
      for (int r = 0; r < 4; ++r) {
        const float ln = __shfl(lrun[m], 4 * lb + r, 64);
        const float inv = 1.f / ln;
        const int q = q0 + m * 16 + 4 * lb + r;
#pragma unroll
        for (int n = 0; n < 4; ++n)
          AO[((size_t)(bb * S + q)) * D + h * DK + n * 16 + lr] = (__bf16)(o[m][n][r] * inv);
      }
  }
}

// ---------------------------------------------------------------------------
// Kernel 3 (m97 structure): out = AO @ Wob^T, f32 output.
// ---------------------------------------------------------------------------
__global__ __launch_bounds__(256) void out_gemm(const __bf16* __restrict__ AOp,
                                                const __bf16* __restrict__ Wb,
                                                float* __restrict__ Out) {
  __shared__ __bf16 As[128 * 64];
  __shared__ __bf16 Bs[128 * 64];
  const int tid = threadIdx.x;
  const int lane = tid & 63;
  const int w = tid >> 6;
  const int wr = w >> 1, wc = w & 1;
  const int lr = lane & 15, lb = lane >> 4;
  const int m0 = blockIdx.x * 128, n0 = blockIdx.y * 128;

  int srow[4], sgcol[4];
#pragma unroll
  for (int rnd = 0; rnd < 4; ++rnd) {
    const int i = rnd * 256 + tid;
    srow[rnd] = i >> 3;
    sgcol[rnd] = ((i & 7) ^ (srow[rnd] & 7)) << 3;
  }

  f32x4 acc[4][4];
#pragma unroll
  for (int i = 0; i < 4; ++i)
#pragma unroll
    for (int j = 0; j < 4; ++j) acc[i][j] = f32x4{0.f, 0.f, 0.f, 0.f};

  for (int k0 = 0; k0 < D; k0 += 64) {
#pragma unroll
    for (int rnd = 0; rnd < 4; ++rnd) {
      GLOAD16(&AOp[(size_t)(m0 + srow[rnd]) * D + k0 + sgcol[rnd]],
              (char*)As + rnd * 4096 + w * 1024);
      GLOAD16(&Wb[(size_t)(n0 + srow[rnd]) * D + k0 + sgcol[rnd]],
              (char*)Bs + rnd * 4096 + w * 1024);
    }
    __syncthreads();

    bf16x8 af[4][2], bfr[4][2];
#pragma unroll
    for (int m = 0; m < 4; ++m) {
      const int row = wr * 64 + m * 16 + lr;
#pragma unroll
      for (int ks = 0; ks < 2; ++ks)
        af[m][ks] = *reinterpret_cast<const bf16x8*>(
            (const char*)As + row * 128 + (((ks * 32 + lb * 8) << 1) ^ ((row & 7) << 4)));
    }
#pragma unroll
    for (int n = 0; n < 4; ++n) {
      const int row = wc * 64 + n * 16 + lr;
#pragma unroll
      for (int ks = 0; ks < 2; ++ks)
        bfr[n][ks] = *reinterpret_cast<const bf16x8*>(
            (const char*)Bs + row * 128 + (((ks * 32 + lb * 8) << 1) ^ ((row & 7) << 4)));
    }
#pragma unroll
    for (int m = 0; m < 4; ++m)
#pragma unroll
      for (int n = 0; n < 4; ++n) {
        acc[m][n] = __builtin_amdgcn_mfma_f32_16x16x32_bf16(af[m][0], bfr[n][0], acc[m][n], 0, 0, 0);
        acc[m][n] = __builtin_amdgcn_mfma_f32_16x16x32_bf16(af[m][1], bfr[n][1], acc[m][n], 0, 0, 0);
      }
    __syncthreads();
  }

#pragma unroll
  for (int m = 0; m < 4; ++m)
#pragma unroll
    for (int n = 0; n < 4; ++n)
#pragma unroll
      for (int r = 0; r < 4; ++r)
        Out[(size_t)(m0 + wr * 64 + m * 16 + lb * 4 + r) * D + n0 + wc * 64 + n * 16 + lr] =
            acc[m][n][r];
}

// ---------------------------------------------------------------------------
extern "C" void kernel_launch(void* const* d_in, const int* in_sizes, int n_in,
                              void* d_out, int out_size, void* d_ws, size_t ws_size,
                              hipStream_t stream) {
  (void)in_sizes; (void)n_in; (void)out_size; (void)ws_size;
  const float* x = (const float*)d_in[0];
  // d_in[1] = causal mask — recomputed analytically, not read
  const float* w_qkv = (const float*)d_in[2];
  const float* b_qkv = (const float*)d_in[3];
  const float* w_o = (const float*)d_in[4];
  float* out = (float*)d_out;

  const size_t qkv_elems = (size_t)B * H * S * DK;  // 8,388,608 (= B*S*D)
  __bf16* Qb = (__bf16*)d_ws;
  __bf16* Kb = Qb + qkv_elems;
  __bf16* VTb = Kb + qkv_elems;
  __bf16* AO = VTb + qkv_elems;
  __bf16* Xb = AO + qkv_elems;
  __bf16* Wqkvb = Xb + (size_t)B * S * D;
  __bf16* Wob = Wqkvb + (size_t)3 * D * D;  // total ~92 MB of workspace

  convert_bf16<<<2048, 256, 0, stream>>>(x, w_qkv, w_o, Xb, Wqkvb, Wob);
  qkv_gemm<<<dim3(64, 24), 256, 0, stream>>>(Xb, Wqkvb, b_qkv, Qb, Kb, VTb);
  attn_fwd<<<dim3(8 * (B * H)), 256, 0, stream>>>(Qb, Kb, VTb, AO);
  out_gemm<<<dim3(64, 8), 256, 0, stream>>>(AO, Wob, out);
}